// Round 9
// baseline (611.694 us; speedup 1.0000x reference)
//
#include <hip/hip_runtime.h>
#include <hip/hip_bf16.h>

// dims
constexpr int BB = 16, IC = 512, OC = 512, HH = 64, WW = 64, HW = 64 * 64, SD = 512;
constexpr float MOD_SCALE = 0.04419417382415922f;      // 1/sqrt(512)
constexpr float CONV_SCALE = 0.014731391274719739f;    // 1/sqrt(512*9)
constexpr float CONV_SCALE2 = 2.170138888888889e-4f;   // 1/4608

typedef float f32x4 __attribute__((ext_vector_type(4)));
typedef short bf16x8 __attribute__((ext_vector_type(8)));

#define VMWAIT(n) asm volatile("s_waitcnt vmcnt(" #n ")" ::: "memory")

__device__ __forceinline__ unsigned short f2bf(float x) {
  __hip_bfloat16 h = __float2bfloat16(x);
  return *(unsigned short*)&h;
}

// ---------------- kernel 1: s[b][ic] = style @ (mod_weight*ms)^T + mod_bias ----
__global__ void k_style(const float* __restrict__ style, const float* __restrict__ mw,
                        const float* __restrict__ mb, float* __restrict__ s) {
  __shared__ float st[SD];
  const int b = blockIdx.x;
  for (int i = threadIdx.x; i < SD; i += 256) st[i] = style[b * SD + i];
  __syncthreads();
  for (int ic = threadIdx.x; ic < IC; ic += 256) {
    const float4* wr = (const float4*)(mw + (size_t)ic * SD);
    float acc = 0.f;
    for (int d = 0; d < SD / 4; ++d) {
      float4 w4 = wr[d];
      float4 s4 = *(const float4*)&st[d * 4];
      acc += w4.x * s4.x + w4.y * s4.y + w4.z * s4.z + w4.w * s4.w;
    }
    s[b * IC + ic] = acc * MOD_SCALE + mb[ic];
  }
}

// ---------------- kernel 2: pack weights [tap][oc][ic] bf16 + w2sum[oc][ic] ----
__global__ void k_pack(const float* __restrict__ w, unsigned short* __restrict__ wpack,
                       float* __restrict__ w2sum) {
  const int oc = blockIdx.x;
  const int ic0 = threadIdx.x * 2;
  const float* p = w + (size_t)oc * IC * 9 + (size_t)ic0 * 9;
  float v[18];
#pragma unroll
  for (int i = 0; i < 18; ++i) v[i] = p[i];
  float s0 = 0.f, s1 = 0.f;
#pragma unroll
  for (int t = 0; t < 9; ++t) { s0 += v[t] * v[t]; s1 += v[9 + t] * v[9 + t]; }
  *(float2*)&w2sum[oc * IC + ic0] = make_float2(s0, s1);
#pragma unroll
  for (int t = 0; t < 9; ++t) {
    unsigned int pk = (unsigned int)f2bf(v[t]) | ((unsigned int)f2bf(v[9 + t]) << 16);
    *(unsigned int*)&wpack[((size_t)t * OC + oc) * IC + ic0] = pk;
  }
}

// ---------------- kernel 3: fscale[b][oc] = conv_scale * rsqrt(cs2*sum + eps) --
__global__ void k_demod(const float* __restrict__ s, const float* __restrict__ w2sum,
                        float* __restrict__ fscale) {
  __shared__ float s2[IC];
  const int b = blockIdx.x;
  for (int i = threadIdx.x; i < IC; i += 256) { float v = s[b * IC + i]; s2[i] = v * v; }
  __syncthreads();
  for (int oc = threadIdx.x; oc < OC; oc += 256) {
    const float4* wr = (const float4*)(w2sum + (size_t)oc * IC);
    float acc = 0.f;
    for (int i4 = 0; i4 < IC / 4; ++i4) {
      float4 w4 = wr[i4];
      float4 q4 = *(const float4*)&s2[i4 * 4];
      acc += w4.x * q4.x + w4.y * q4.y + w4.z * q4.z + w4.w * q4.w;
    }
    fscale[b * OC + oc] = CONV_SCALE * rsqrtf(CONV_SCALE2 * acc + 1e-8f);
  }
}

// ---------------- kernel 4: the conv (implicit GEMM, bf16 MFMA) ----------------
// grid: 2048 = 16 b * 4 mblk * 32 nblk; block 256 = 4 waves.
// Block tile: 128 oc x 128 px. Wave w owns 32 oc x 128 px — and issueA has wave w
// DMA exactly rows [32w,32w+32): A is WAVE-PRIVATE. Own-wave vmcnt retirement
// guarantees the LDS write landed (m135), so NO per-tap barriers at all. Barriers
// only at the icb boundary (2/icb) around the shared-B restage. Waves drift up to
// 9 taps -> TLP covers the ds-latency + MFMA chains. Same 3-buffer/2-ahead/
// vmcnt(2) ladder, B geometry, stageB, and grid as the proven r3/r7 base.
// Register budget: acc[2][8]=64 AGPR + ~40 frag VGPR (2 A + 8 B) < r7's footprint.
__global__ __launch_bounds__(256, 3) void k_conv(
    const float* __restrict__ x, const unsigned short* __restrict__ wpack,
    const float* __restrict__ s, const float* __restrict__ fscale,
    float* __restrict__ out) {
  __shared__ __align__(128) unsigned short Asm[3][128 * 32];  // [buf][oc_local][ic] swizzled
  __shared__ __align__(128) unsigned short Bsm[264 * 32];     // [h''*66 + w''][ic] swizzled

  const int bx = blockIdx.x;
  const int b = bx >> 7;
  const int mblk = (bx >> 5) & 3;
  const int nblk = bx & 31;

  const int tid = threadIdx.x;
  const int wave = tid >> 6, lane = tid & 63;
  const int lrow = lane & 15, lk = lane >> 4;

  const int h0 = nblk * 2;  // this block's 2 output rows; halo rows h0-1..h0+2
  const float* xb = x + (size_t)b * IC * HW;
  const float* sb = s + b * IC;

  f32x4 acc[2][8];
#pragma unroll
  for (int i = 0; i < 2; ++i)
#pragma unroll
    for (int j = 0; j < 8; ++j) acc[i][j] = f32x4{0.f, 0.f, 0.f, 0.f};

  // zero the w-halo rows (w''==0 and w''==65 for the 4 h rows), once
  {
    int q = tid >> 5;  // 0..7
    int hh = q >> 1, wz = (q & 1) ? 65 : 0;
    Bsm[(hh * 66 + wz) * 32 + (tid & 31)] = 0;
  }

  // stage input tile for one 32-ic block: [4 h rows][64 w][32 ic], scaled by s
  // (identical to r3/r7 — direct load -> ds_write, no cross-phase registers)
  auto stageB = [&](int icb) {
    const int hh = wave;     // 0..3
    const int w = lane;      // 0..63
    const int h_abs = h0 - 1 + hh;
    const bool vh = (h_abs >= 0) && (h_abs < HH);
    const int h_safe = vh ? h_abs : 0;
    const int r = hh * 66 + w + 1;
    const int swz = (r >> 1) & 3;
    const float* src = xb + (size_t)(icb * 32) * HW + h_safe * WW + w;
#pragma unroll
    for (int c = 0; c < 4; ++c) {
      unsigned int pk[4];
#pragma unroll
      for (int jj = 0; jj < 4; ++jj) {
        int ic = c * 8 + jj * 2;
        float m0 = vh ? sb[icb * 32 + ic] : 0.f;
        float m1 = vh ? sb[icb * 32 + ic + 1] : 0.f;
        float v0 = src[(size_t)ic * HW] * m0;
        float v1 = src[(size_t)(ic + 1) * HW] * m1;
        pk[jj] = (unsigned int)f2bf(v0) | ((unsigned int)f2bf(v1) << 16);
      }
      int cd = c ^ swz;
      *(uint4*)&Bsm[r * 32 + cd * 8] = make_uint4(pk[0], pk[1], pk[2], pk[3]);
    }
  };

  // wave-private A DMA: wave w writes rows [32w,32w+32) (2 vmem ops per call),
  // which are exactly the rows wave w reads in its MFMA taps.
  auto issueA = [&](int tap, int icb, int nb) {
    const unsigned short* base =
        wpack + ((size_t)(tap * OC + mblk * 128)) * IC + icb * 32;
#pragma unroll
    for (int q = 0; q < 2; ++q) {
      int r = wave * 32 + q * 16 + (lane >> 2);
      int cs = (lane & 3) ^ ((r >> 1) & 3);
      const unsigned short* g = base + (size_t)r * IC + cs * 8;
      unsigned short* l = &Asm[nb][(wave * 32 + q * 16) * 32];
      __builtin_amdgcn_global_load_lds(
          (const __attribute__((address_space(1))) void*)g,
          (__attribute__((address_space(3))) void*)l, 16, 0, 0);
    }
  };

  stageB(0);
  issueA(0, 0, 0);   // D(0) -> buf0
  issueA(1, 0, 1);   // D(1) -> buf1
  __syncthreads();   // prologue only: full drain + publish Bsm(0)

  for (int icb = 0; icb < 16; ++icb) {
#pragma unroll
    for (int t = 0; t < 9; ++t) {
      // ---- per-wave arrival wait for OWN D(t): D(t) is the oldest possible
      //      outstanding op, one younger group (2 ops) may remain ----
      if (icb == 15 && t == 8) { VMWAIT(0); } else { VMWAIT(2); }
      __builtin_amdgcn_sched_barrier(0);

      // ---- issue D(t+2) into buf (t+2)%3: wave-private rows; this wave's
      //      reads of that buffer (tap t-1) precede this point in program
      //      order and their ds_reads are memory-ordered before the asm ----
      if (t <= 6) {
        issueA(t + 2, icb, (t + 2) % 3);
      } else if (icb < 15) {
        issueA(t - 7, icb + 1, t - 7);       // t==7 -> tap0/buf0, t==8 -> tap1/buf1
      }

      // ---- A-frags from own slice; B-frags for this tap ----
      bf16x8 af0, af1;
      {
        int r0 = wave * 32 + lrow;
        int r1 = wave * 32 + 16 + lrow;
        af0 = *(const bf16x8*)&Asm[t % 3][r0 * 32 + ((lk ^ ((r0 >> 1) & 3)) * 8)];
        af1 = *(const bf16x8*)&Asm[t % 3][r1 * 32 + ((lk ^ ((r1 >> 1) & 3)) * 8)];
      }
      const int dh = t / 3 - 1, dw = t % 3 - 1;
      bf16x8 bfr[8];
#pragma unroll
      for (int j = 0; j < 8; ++j) {
        int hb = (j >> 2) + dh + 1;                     // 0..3
        int r = hb * 66 + (j & 3) * 16 + lrow + dw + 1;
        bfr[j] = *(const bf16x8*)&Bsm[r * 32 + ((lk ^ ((r >> 1) & 3)) * 8)];
      }

      __builtin_amdgcn_s_setprio(1);
#pragma unroll
      for (int j = 0; j < 8; ++j)
        acc[0][j] = __builtin_amdgcn_mfma_f32_16x16x32_bf16(af0, bfr[j], acc[0][j], 0, 0, 0);
#pragma unroll
      for (int j = 0; j < 8; ++j)
        acc[1][j] = __builtin_amdgcn_mfma_f32_16x16x32_bf16(af1, bfr[j], acc[1][j], 0, 0, 0);
      __builtin_amdgcn_s_setprio(0);
      // NO barrier: A is wave-private, Bsm is stable until the icb boundary
    }

    // ---- icb boundary: the only block-wide sync ----
    if (icb < 15) {
      __builtin_amdgcn_s_barrier();          // all waves done reading Bsm(icb)
      __builtin_amdgcn_sched_barrier(0);
      stageB(icb + 1);                       // x loads auto-waited; older DMA unaffected logically
      asm volatile("s_waitcnt lgkmcnt(0)" ::: "memory");
      __builtin_amdgcn_sched_barrier(0);
      __builtin_amdgcn_s_barrier();          // publish Bsm(icb+1)
    }
  }

  // epilogue: scale by conv_scale*demod[b][oc], coalesced 64B stores
  const float* fsb = fscale + b * OC;
#pragma unroll
  for (int i = 0; i < 2; ++i) {
#pragma unroll
    for (int rr = 0; rr < 4; ++rr) {
      const int oc = mblk * 128 + wave * 32 + i * 16 + lk * 4 + rr;
      const float sc = fsb[oc];
      float* obase = out + ((size_t)(b * OC + oc)) * HW + nblk * 128;
#pragma unroll
      for (int j = 0; j < 8; ++j) {
        obase[(j >> 2) * WW + (j & 3) * 16 + lrow] = acc[i][j][rr] * sc;
      }
    }
  }
}

// ---------------- launch --------------------------------------------------------
extern "C" void kernel_launch(void* const* d_in, const int* in_sizes, int n_in,
                              void* d_out, int out_size, void* d_ws, size_t ws_size,
                              hipStream_t stream) {
  const float* input = (const float*)d_in[0];       // [16,512,64,64]
  const float* style = (const float*)d_in[1];       // [16,512]
  const float* weight = (const float*)d_in[2];      // [1,512,512,3,3]
  const float* mod_weight = (const float*)d_in[3];  // [512,512]
  const float* mod_bias = (const float*)d_in[4];    // [512]
  float* out = (float*)d_out;

  char* ws = (char*)d_ws;
  constexpr size_t WPACK_B = (size_t)9 * OC * IC * 2;   // 4,718,592
  constexpr size_t W2SUM_B = (size_t)OC * IC * 4;       // 1,048,576
  constexpr size_t S_B = (size_t)BB * IC * 4;           // 32,768
  unsigned short* wpack = (unsigned short*)ws;
  float* w2sum = (float*)(ws + WPACK_B);
  float* s = (float*)(ws + WPACK_B + W2SUM_B);
  float* fscale = (float*)(ws + WPACK_B + W2SUM_B + S_B);

  k_style<<<BB, 256, 0, stream>>>(style, mod_weight, mod_bias, s);
  k_pack<<<OC, 256, 0, stream>>>(weight, wpack, w2sum);
  k_demod<<<BB, 256, 0, stream>>>(s, w2sum, fscale);
  k_conv<<<2048, 256, 0, stream>>>(input, wpack, s, fscale, out);
}

// Round 10
// 460.636 us; speedup vs baseline: 1.3279x; 1.3279x over previous
//
#include <hip/hip_runtime.h>
#include <hip/hip_bf16.h>

// dims
constexpr int BB = 16, IC = 512, OC = 512, HH = 64, WW = 64, HW = 64 * 64, SD = 512;
constexpr float MOD_SCALE = 0.04419417382415922f;      // 1/sqrt(512)
constexpr float CONV_SCALE = 0.014731391274719739f;    // 1/sqrt(512*9)
constexpr float CONV_SCALE2 = 2.170138888888889e-4f;   // 1/4608

typedef float f32x4 __attribute__((ext_vector_type(4)));
typedef short bf16x8 __attribute__((ext_vector_type(8)));

#define VMWAIT(n) asm volatile("s_waitcnt vmcnt(" #n ")" ::: "memory")

__device__ __forceinline__ unsigned short f2bf(float x) {
  __hip_bfloat16 h = __float2bfloat16(x);
  return *(unsigned short*)&h;
}

// ---------------- kernel 1: s[b][ic] = style @ (mod_weight*ms)^T + mod_bias ----
__global__ void k_style(const float* __restrict__ style, const float* __restrict__ mw,
                        const float* __restrict__ mb, float* __restrict__ s) {
  __shared__ float st[SD];
  const int b = blockIdx.x;
  for (int i = threadIdx.x; i < SD; i += 256) st[i] = style[b * SD + i];
  __syncthreads();
  for (int ic = threadIdx.x; ic < IC; ic += 256) {
    const float4* wr = (const float4*)(mw + (size_t)ic * SD);
    float acc = 0.f;
    for (int d = 0; d < SD / 4; ++d) {
      float4 w4 = wr[d];
      float4 s4 = *(const float4*)&st[d * 4];
      acc += w4.x * s4.x + w4.y * s4.y + w4.z * s4.z + w4.w * s4.w;
    }
    s[b * IC + ic] = acc * MOD_SCALE + mb[ic];
  }
}

// ---------------- kernel 2: pack weights [tap][oc][ic] bf16 + w2sum[oc][ic] ----
__global__ void k_pack(const float* __restrict__ w, unsigned short* __restrict__ wpack,
                       float* __restrict__ w2sum) {
  const int oc = blockIdx.x;
  const int ic0 = threadIdx.x * 2;
  const float* p = w + (size_t)oc * IC * 9 + (size_t)ic0 * 9;
  float v[18];
#pragma unroll
  for (int i = 0; i < 18; ++i) v[i] = p[i];
  float s0 = 0.f, s1 = 0.f;
#pragma unroll
  for (int t = 0; t < 9; ++t) { s0 += v[t] * v[t]; s1 += v[9 + t] * v[9 + t]; }
  *(float2*)&w2sum[oc * IC + ic0] = make_float2(s0, s1);
#pragma unroll
  for (int t = 0; t < 9; ++t) {
    unsigned int pk = (unsigned int)f2bf(v[t]) | ((unsigned int)f2bf(v[9 + t]) << 16);
    *(unsigned int*)&wpack[((size_t)t * OC + oc) * IC + ic0] = pk;
  }
}

// ---------------- kernel 3: fscale[b][oc] = conv_scale * rsqrt(cs2*sum + eps) --
__global__ void k_demod(const float* __restrict__ s, const float* __restrict__ w2sum,
                        float* __restrict__ fscale) {
  __shared__ float s2[IC];
  const int b = blockIdx.x;
  for (int i = threadIdx.x; i < IC; i += 256) { float v = s[b * IC + i]; s2[i] = v * v; }
  __syncthreads();
  for (int oc = threadIdx.x; oc < OC; oc += 256) {
    const float4* wr = (const float4*)(w2sum + (size_t)oc * IC);
    float acc = 0.f;
    for (int i4 = 0; i4 < IC / 4; ++i4) {
      float4 w4 = wr[i4];
      float4 q4 = *(const float4*)&s2[i4 * 4];
      acc += w4.x * q4.x + w4.y * q4.y + w4.z * q4.z + w4.w * q4.w;
    }
    fscale[b * OC + oc] = CONV_SCALE * rsqrtf(CONV_SCALE2 * acc + 1e-8f);
  }
}

// B-frag read for tap TN into named local array DST[4] (static indices only)
#define LOADB(DST, TN)                                                         \
  do {                                                                         \
    const int dh_ = (TN) / 3 - 1, dw_ = (TN) % 3 - 1;                          \
    const int hb_ = wn + dh_ + 1;                                              \
    _Pragma("unroll") for (int j_ = 0; j_ < 4; ++j_) {                         \
      int r_ = hb_ * 66 + j_ * 16 + lrow + dw_ + 1;                            \
      DST[j_] = *(const bf16x8*)&Bsm[r_ * 32 + ((lk ^ ((r_ >> 1) & 3)) * 8)];  \
    }                                                                          \
  } while (0)

// ---------------- kernel 4: the conv (implicit GEMM, bf16 MFMA) ----------------
// grid: 2048 = 16 b * 4 mblk * 32 nblk (XCD-swizzled); block 256 (4 waves, 2x2).
// FAT PHASES: 3 taps per phase -> 48 phases total (vs 144). Full lockstep kept
// (locality is load-bearing: r4/r9 showed drift doubles FETCH). A staged in two
// 3-buffer halves (6 x 8KB); during phase P (half H) we issue phase P+1's 6 DMA
// ops into half 1-H (safe: barrier(P) proved half 1-H was consumed in P-1).
// At phase start the ONLY outstanding vmem ops are this phase's 6 -> VMWAIT(0)
// is a counted-exact drain with ~2500 cyc of issue-to-wait slack.
// T1 XCD swizzle: same-b blocks share an XCD L2.
__global__ __launch_bounds__(256, 2) void k_conv(
    const float* __restrict__ x, const unsigned short* __restrict__ wpack,
    const float* __restrict__ s, const float* __restrict__ fscale,
    float* __restrict__ out) {
  __shared__ __align__(128) unsigned short Asm[6][128 * 32];  // [buf][oc_local][ic] swizzled
  __shared__ __align__(128) unsigned short Bsm[264 * 32];     // [h''*66 + w''][ic] swizzled

  // XCD-aware swizzle (2048 = 8 * 256, bijective): XCD k gets logical ids
  // k*256..k*256+255 = two full b values -> per-phase x working set fits L2.
  const int bx = ((blockIdx.x & 7) << 8) | (blockIdx.x >> 3);
  const int b = bx >> 7;
  const int mblk = (bx >> 5) & 3;
  const int nblk = bx & 31;

  const int tid = threadIdx.x;
  const int wave = tid >> 6, lane = tid & 63;
  const int wm = wave >> 1, wn = wave & 1;
  const int lrow = lane & 15, lk = lane >> 4;

  const int h0 = nblk * 2;  // this block's 2 output rows; halo rows h0-1..h0+2
  const float* xb = x + (size_t)b * IC * HW;
  const float* sb = s + b * IC;

  f32x4 acc[4][4];
#pragma unroll
  for (int i = 0; i < 4; ++i)
#pragma unroll
    for (int j = 0; j < 4; ++j) acc[i][j] = f32x4{0.f, 0.f, 0.f, 0.f};

  // zero the w-halo rows (w''==0 and w''==65 for the 4 h rows), once
  {
    int q = tid >> 5;  // 0..7
    int hh = q >> 1, wz = (q & 1) ? 65 : 0;
    Bsm[(hh * 66 + wz) * 32 + (tid & 31)] = 0;
  }

  // stage input tile for one 32-ic block: [4 h rows][64 w][32 ic], scaled by s
  auto stageB = [&](int icb) {
    const int hh = wave;     // 0..3
    const int w = lane;      // 0..63
    const int h_abs = h0 - 1 + hh;
    const bool vh = (h_abs >= 0) && (h_abs < HH);
    const int h_safe = vh ? h_abs : 0;
    const int r = hh * 66 + w + 1;
    const int swz = (r >> 1) & 3;
    const float* src = xb + (size_t)(icb * 32) * HW + h_safe * WW + w;
#pragma unroll
    for (int c = 0; c < 4; ++c) {
      unsigned int pk[4];
#pragma unroll
      for (int jj = 0; jj < 4; ++jj) {
        int ic = c * 8 + jj * 2;
        float m0 = vh ? sb[icb * 32 + ic] : 0.f;
        float m1 = vh ? sb[icb * 32 + ic + 1] : 0.f;
        float v0 = src[(size_t)ic * HW] * m0;
        float v1 = src[(size_t)(ic + 1) * HW] * m1;
        pk[jj] = (unsigned int)f2bf(v0) | ((unsigned int)f2bf(v1) << 16);
      }
      int cd = c ^ swz;
      *(uint4*)&Bsm[r * 32 + cd * 8] = make_uint4(pk[0], pk[1], pk[2], pk[3]);
    }
  };

  // async-stage one 128x32 weight tile (2 global_load_lds per wave per call)
  auto issueA = [&](int tap, int icb, int nb) {
    const unsigned short* base =
        wpack + ((size_t)(tap * OC + mblk * 128)) * IC + icb * 32;
#pragma unroll
    for (int q = 0; q < 2; ++q) {
      int r = wave * 32 + q * 16 + (lane >> 2);
      int cs = (lane & 3) ^ ((r >> 1) & 3);
      const unsigned short* g = base + (size_t)r * IC + cs * 8;
      unsigned short* l = &Asm[nb][(wave * 32 + q * 16) * 32];
      __builtin_amdgcn_global_load_lds(
          (const __attribute__((address_space(1))) void*)g,
          (__attribute__((address_space(3))) void*)l, 16, 0, 0);
    }
  };
  // issue one 3-tap group (6 vmem ops) into half hf
  auto issueA3 = [&](int tb, int icb, int hf) {
#pragma unroll
    for (int i = 0; i < 3; ++i) issueA(tb + i, icb, hf * 3 + i);
  };

  stageB(0);
  issueA3(0, 0, 0);   // phase 0 group (taps 0..2) -> half 0
  __syncthreads();    // prologue only: full drain + publish Bsm(0)

  for (int icb = 0; icb < 16; ++icb) {
#pragma unroll
    for (int k = 0; k < 3; ++k) {              // 3 fat phases per icb
      const int gp = icb * 3 + k;              // global phase id, 0..47
      const int half = gp & 1;

      // ---- arrival: exactly this phase's 6 DMA ops are outstanding ----
      VMWAIT(0);
      __builtin_amdgcn_s_barrier();
      __builtin_amdgcn_sched_barrier(0);

      if (k == 0 && icb > 0) {
        // restage B; no DMA outstanding here, so the x-loads' compiler
        // auto-waits couple to nothing else.
        stageB(icb);
        asm volatile("s_waitcnt lgkmcnt(0)" ::: "memory");
        __builtin_amdgcn_s_barrier();          // publish new Bsm
        __builtin_amdgcn_sched_barrier(0);
      }

      // ---- issue next phase's group into the other half ----
      if (gp < 47) {
        const int nk = (k + 1) % 3;
        const int nicb = icb + (k == 2 ? 1 : 0);
        issueA3(nk * 3, nicb, 1 - half);
      }

      // ---- compute 3 taps from half's bufs; Bsm stable all phase ----
#pragma unroll
      for (int i = 0; i < 3; ++i) {
        const int tt = k * 3 + i;              // tap 0..8 (compile-time)
        bf16x8 af[4];
#pragma unroll
        for (int ii = 0; ii < 4; ++ii) {
          int r = wm * 64 + ii * 16 + lrow;
          af[ii] = *(const bf16x8*)&Asm[half * 3 + i]
                       [r * 32 + ((lk ^ ((r >> 1) & 3)) * 8)];
        }
        bf16x8 bfr[4];
        LOADB(bfr, tt);
        __builtin_amdgcn_s_setprio(1);
#pragma unroll
        for (int ii = 0; ii < 4; ++ii)
#pragma unroll
          for (int j = 0; j < 4; ++j)
            acc[ii][j] = __builtin_amdgcn_mfma_f32_16x16x32_bf16(
                af[ii], bfr[j], acc[ii][j], 0, 0, 0);
        __builtin_amdgcn_s_setprio(0);
      }
      __builtin_amdgcn_sched_barrier(0);
    }
  }

  // epilogue: scale by conv_scale*demod[b][oc], coalesced 64B stores
  const float* fsb = fscale + b * OC;
#pragma unroll
  for (int i = 0; i < 4; ++i) {
#pragma unroll
    for (int rr = 0; rr < 4; ++rr) {
      const int oc = mblk * 128 + wm * 64 + i * 16 + lk * 4 + rr;
      const float sc = fsb[oc];
      float* orow = out + ((size_t)(b * OC + oc)) * HW + nblk * 128 + wn * 64 + lrow;
#pragma unroll
      for (int j = 0; j < 4; ++j) orow[j * 16] = acc[i][j][rr] * sc;
    }
  }
}

// ---------------- launch --------------------------------------------------------
extern "C" void kernel_launch(void* const* d_in, const int* in_sizes, int n_in,
                              void* d_out, int out_size, void* d_ws, size_t ws_size,
                              hipStream_t stream) {
  const float* input = (const float*)d_in[0];       // [16,512,64,64]
  const float* style = (const float*)d_in[1];       // [16,512]
  const float* weight = (const float*)d_in[2];      // [1,512,512,3,3]
  const float* mod_weight = (const float*)d_in[3];  // [512,512]
  const float* mod_bias = (const float*)d_in[4];    // [512]
  float* out = (float*)d_out;

  char* ws = (char*)d_ws;
  constexpr size_t WPACK_B = (size_t)9 * OC * IC * 2;   // 4,718,592
  constexpr size_t W2SUM_B = (size_t)OC * IC * 4;       // 1,048,576
  constexpr size_t S_B = (size_t)BB * IC * 4;           // 32,768
  unsigned short* wpack = (unsigned short*)ws;
  float* w2sum = (float*)(ws + WPACK_B);
  float* s = (float*)(ws + WPACK_B + W2SUM_B);
  float* fscale = (float*)(ws + WPACK_B + W2SUM_B + S_B);

  k_style<<<BB, 256, 0, stream>>>(style, mod_weight, mod_bias, s);
  k_pack<<<OC, 256, 0, stream>>>(weight, wpack, w2sum);
  k_demod<<<BB, 256, 0, stream>>>(s, w2sum, fscale);
  k_conv<<<2048, 256, 0, stream>>>(input, wpack, s, fscale, out);
}